// Round 3
// 175.825 us; speedup vs baseline: 1.0625x; 1.0625x over previous
//
#include <hip/hip_runtime.h>
#include <cmath>
#include <cstdint>
#include <cstring>

// Problem constants (B,C,H,W) = (16,3,512,512), window 11, patch 16.
#define OUTD 502          // 512 - 11 + 1
#define TSX  64           // output tile width
#define TSY  16           // output tile height
#define SPITCH 88         // staged row pitch (f16): 176 B, 16B-mult
#define SROWS  32         // 26 data rows + 6 zero pad (B-frag k reaches 31)
#define HTP    40         // per-wave transpose buffer pitch (f16): 80 B, 16B-mult
#define NTAP 11
#define GX   8            // ceil(502/64)
#define GY   32           // ceil(502/16)
#define NPARTIAL (48 * GY * GX)   // 12288

typedef float    f32x4 __attribute__((ext_vector_type(4)));
typedef _Float16 f16x4 __attribute__((ext_vector_type(4)));
typedef _Float16 f16x8 __attribute__((ext_vector_type(8)));

struct GW { float g[NTAP]; float cm; };  // g: fp16-rounded weights; cm = 1/(sum g)^2

__device__ __forceinline__ f32x4 mfma_f16(f16x8 a, f16x8 b, f32x4 c) {
    return __builtin_amdgcn_mfma_f32_16x16x32_f16(a, b, c, 0, 0, 0);
}

// Kernel 1: per-patch (16x16) max of the int mask -> small[b][32][32]
__global__ __launch_bounds__(256) void patch_max_kernel(const int* __restrict__ mask,
                                                        int* __restrict__ smallbuf) {
    const int py = blockIdx.x;   // 0..31 patch row
    const int b  = blockIdx.y;   // 0..15 image
    const int tid = threadIdx.x;
    const int lane = tid & 63, wv = tid >> 6;
    const int4* m4 = (const int4*)(mask + ((size_t)b << 18) + (size_t)py * 16 * 512);
    #pragma unroll
    for (int j = 0; j < 8; ++j) {
        int px  = wv + 4 * j;
        int row = lane >> 2, q = lane & 3;
        int4 v = m4[row * 128 + px * 4 + q];
        int mx = max(max(v.x, v.y), max(v.z, v.w));
        #pragma unroll
        for (int off = 32; off >= 1; off >>= 1) mx = max(mx, __shfl_xor(mx, off));
        if (lane == 0) smallbuf[((b << 5) + py) * 32 + px] = mx;
    }
}

// Kernel 2: MFMA-based separable-Gaussian SSIM over a 64x16 output tile.
// Both 11-tap convolutions are 16x16x32 *fp16* MFMAs with a Toeplitz A
// (A[m][k] = g[k-m]). fp16 (not bf16) for the whole data path: bf16's
// coarse ulp gave a ~0.02-ulp systematic bias that failed absmax (R8).
// This revision removes the three biggest VALU blocks (kernel is
// VALU-issue-bound: VALUBusy ~70%, MfmaUtil ~4.6%):
//  (a) A-frag built from a 48-entry padded LDS tap table (8 ds_read_u16)
//      instead of an 88-way cmp/cndmask chain (~176 VALU -> ~10).
//  (b) P = a*b and S = a*a+b*b computed directly with packed f16 ops.
//      v_pk_mul_f16 is the same correctly-rounded RTNE product the old
//      f32 round-trip produced (22-bit product exact in f32); S gains one
//      extra unbiased fp16 RTNE rounding on a^2 (noise-level, not bias).
//  (c) epilogue valid-mask hoisted (vm0/vm1 once per thread, select per row).
__global__ __launch_bounds__(256) void ssim_kernel(const float* __restrict__ img1,
                                                   const float* __restrict__ img2,
                                                   const int* __restrict__ smallbuf,
                                                   float* __restrict__ partial, GW gw) {
    __shared__ _Float16 sA[2][SROWS][SPITCH];   // 11264 B: staged img1/img2 (f16)
    __shared__ _Float16 sHT[4][16][HTP];        //  5120 B: per-wave transpose buffers
    __shared__ _Float16 gpad[48];               // zero-padded taps: gpad[15+i]=g[i]
    __shared__ int sdil[10];                    // 2 patch-rows x 5 patch-cols
    __shared__ float wsum[4];

    const int tid  = threadIdx.x;
    const int wv   = tid >> 6, lane = tid & 63;
    const int nidx = lane & 15, quad = lane >> 4;
    const int x0 = blockIdx.x * TSX, y0 = blockIdx.y * TSY;
    const int bc = blockIdx.z;               // b*3 + c
    const size_t base = (size_t)bc << 18;    // *512*512

    // Phase 0: stage both images, rows 0..25 from global (clamped addresses:
    // clamped data only ever reaches discarded outputs), rows 26..31 zeroed
    // (finite pad for B-frag over-reads; A is zero there anyway).
    for (int i = tid; i < SROWS * 20; i += 256) {   // 640 slots
        int r = i / 20, q = i - r * 20;
        if (r < 26) {
            int gy = y0 + r;     gy = gy > 511 ? 511 : gy;
            int gx = x0 + 4 * q; gx = gx > 508 ? 508 : gx;
            size_t off = base + ((size_t)gy << 9) + gx;
            f32x4 a = *(const f32x4*)(img1 + off);
            f32x4 b = *(const f32x4*)(img2 + off);
            *(f16x4*)&sA[0][r][4 * q] = __builtin_convertvector(a, f16x4);
            *(f16x4*)&sA[1][r][4 * q] = __builtin_convertvector(b, f16x4);
        } else {
            f16x4 z = {};
            *(f16x4*)&sA[0][r][4 * q] = z;
            *(f16x4*)&sA[1][r][4 * q] = z;
        }
    }

    // padded tap table (indices 15..25 hold g[0..10], rest zero)
    if (tid < 48) {
        int k = tid - 15;
        int kc = k < 0 ? 0 : (k > 10 ? 10 : k);      // clamp: no speculative OOB
        gpad[tid] = (k == kc) ? (_Float16)gw.g[kc] : (_Float16)0.f;
    }

    // fused 3x3 dilation lookup for this tile's patch neighborhood
    if (tid >= 192 && tid < 202) {
        int t = tid - 192;
        int pr = (int)blockIdx.y + (t >= 5 ? 1 : 0);       // y0>>4 == blockIdx.y
        int pc = (int)blockIdx.x * 4 + (t >= 5 ? t - 5 : t);
        int acc = 0;
        if (pr < 32 && pc < 32) {
            const int* sb = smallbuf + ((bc / 3) << 10);
            #pragma unroll
            for (int dy = -1; dy <= 1; ++dy)
                #pragma unroll
                for (int dx = -1; dx <= 1; ++dx) {
                    int ny = pr + dy, nx = pc + dx;
                    if (ny >= 0 && ny < 32 && nx >= 0 && nx < 32) acc |= sb[(ny << 5) + nx];
                }
        }
        sdil[t] = acc ? 1 : 0;
    }
    __syncthreads();

    // Toeplitz A-frag (shared by both passes): A[m=nidx][k=quad*8+j] = g[k-m].
    // The 8 taps are consecutive entries of the padded table starting at
    // quad*8 - nidx + 15 (in [0,39]): one address + 8 ds_read_u16.
    f16x8 af;
    {
        const _Float16* gp = &gpad[quad * 8 - nidx + 15];
        #pragma unroll
        for (int j = 0; j < 8; ++j) af[j] = gp[j];
    }

    // This wave handles output cols cb..cb+15 of the tile.
    const int cb = 16 * wv;

    // Load raw a/b B-frags (2 row-halves each): lane = row 16h+nidx,
    // cols cb + quad*8 .. +7 (contiguous, 16B-aligned). P/S in packed f16.
    f16x8 fr0[4], fr1[4];
    #pragma unroll
    for (int h = 0; h < 2; ++h) {
        f16x8 a = *(const f16x8*)&sA[0][16 * h + nidx][cb + quad * 8];
        f16x8 b = *(const f16x8*)&sA[1][16 * h + nidx][cb + quad * 8];
        f16x8 P = a * b;                 // v_pk_mul_f16: RTNE, == old f32 path
        f16x8 S = a * a + b * b;         // pk mul+fma: one extra RTNE on a^2
        if (h == 0) { fr0[0] = a; fr0[1] = b; fr0[2] = P; fr0[3] = S; }
        else        { fr1[0] = a; fr1[1] = b; fr1[2] = P; fr1[3] = S; }
    }

    // Per map: 2 horizontal MFMAs -> transpose through sHT[wv] -> 1 vertical MFMA.
    // All LDS deps are intra-wave (in-order DS pipe + compiler lgkmcnt waits).
    f32x4 accv[4];
    #pragma unroll
    for (int mm = 0; mm < 4; ++mm) {
        f32x4 z = {0.f, 0.f, 0.f, 0.f};
        f32x4 c0 = mfma_f16(af, fr0[mm], z);   // rows 0..15
        f32x4 c1 = mfma_f16(af, fr1[mm], z);   // rows 16..31
        // C layout: row(m=x') = quad*4+r, col(n=y) = nidx
        #pragma unroll
        for (int r = 0; r < 4; ++r) {
            sHT[wv][quad * 4 + r][nidx]      = (_Float16)c0[r];
            sHT[wv][quad * 4 + r][16 + nidx] = (_Float16)c1[r];
        }
        // B2[k=quad*8+j][n=x'=nidx] = sHT[wv][nidx][k] (contiguous, aligned)
        f16x8 hb = *(const f16x8*)&sHT[wv][nidx][quad * 8];
        accv[mm] = mfma_f16(af, hb, z);
    }

    // Epilogue: lane holds 4 maps x 4 pixels at y = y0+quad*4+r, x = x0+cb+nidx
    const float C1v = 1e-4f, C2v = 9e-4f;  // L = 1 (inputs uniform [0,1))
    const float cm = gw.cm;
    float lsum = 0.f;
    {
        const int xl = cb + nidx;
        const int x = x0 + xl;
        if (x < OUTD) {
            const int lc0 = xl >> 4, lc1 = (xl + 10) >> 4;
            const int vm0 = sdil[lc0] & sdil[lc1];
            const int vm1 = vm0 & sdil[5 + lc0] & sdil[5 + lc1];
            #pragma unroll
            for (int r = 0; r < 4; ++r) {
                int yl = quad * 4 + r;
                int y = y0 + yl;
                if (y < OUTD) {
                    // lr1 = (yl+10)>>4 is 1 iff yl >= 6
                    int validm = (yl >= 6) ? vm1 : vm0;
                    float mu1 = accv[0][r] * cm, mu2 = accv[1][r] * cm;
                    float Sab = accv[2][r] * cm, Sss = accv[3][r] * cm;
                    float mu1s = mu1 * mu1, mu2s = mu2 * mu2, mu12 = mu1 * mu2;
                    float sg12 = Sab - mu12;
                    float sigS = Sss - mu1s - mu2s;
                    float num = (2.f * mu12 + C1v) * (2.f * sg12 + C2v);
                    float den = (mu1s + mu2s + C1v) * (sigS + C2v);
                    if (validm) lsum += __fdividef(num, den);
                }
            }
        }
    }

    // block reduction -> one float partial per block (deterministic, no atomics)
    #pragma unroll
    for (int off = 32; off >= 1; off >>= 1) lsum += __shfl_xor(lsum, off);
    if ((tid & 63) == 0) wsum[tid >> 6] = lsum;
    __syncthreads();
    if (tid == 0)
        partial[((int)blockIdx.z * GY + (int)blockIdx.y) * GX + (int)blockIdx.x] =
            wsum[0] + wsum[1] + wsum[2] + wsum[3];
}

// Kernel 3: reduce partials, divide by element count
__global__ __launch_bounds__(256) void finalize_kernel(const float* __restrict__ partial,
                                                       float* __restrict__ out) {
    __shared__ double sd[256];
    double s = 0.0;
    const f32x4* p4 = (const f32x4*)partial;
    for (int i = threadIdx.x; i < NPARTIAL / 4; i += 256) {
        f32x4 vv = p4[i];
        s += (double)vv.x + (double)vv.y + (double)vv.z + (double)vv.w;
    }
    sd[threadIdx.x] = s;
    __syncthreads();
    for (int st = 128; st >= 1; st >>= 1) {
        if (threadIdx.x < st) sd[threadIdx.x] += sd[threadIdx.x + st];
        __syncthreads();
    }
    if (threadIdx.x == 0) out[0] = (float)(sd[0] / 12096192.0);  // 16*3*502*502
}

// Round a positive normal double to the nearest fp16-representable float (RTNE).
static inline float fp16_rtne(double x) {
    float f = (float)x;
    uint32_t u; memcpy(&u, &f, 4);
    // drop 13 mantissa bits (23 -> 10), RTNE with carry into exponent
    u = (u + 0xFFFu + ((u >> 13) & 1u)) & ~0x1FFFu;
    memcpy(&f, &u, 4);
    return f;
}

extern "C" void kernel_launch(void* const* d_in, const int* in_sizes, int n_in,
                              void* d_out, int out_size, void* d_ws, size_t ws_size,
                              hipStream_t stream) {
    const float* img1 = (const float*)d_in[0];
    const float* img2 = (const float*)d_in[1];
    const int*   mask = (const int*)d_in[2];
    float* out = (float*)d_out;

    char* ws = (char*)d_ws;
    float* partial  = (float*)ws;                        // 12288 floats
    int*   smallbuf = (int*)(ws + NPARTIAL * 4);         // 16*32*32 ints

    // Gaussian(sigma=1.5), normalized in double, then each tap rounded to
    // fp16 (RTNE). cm = 1/(sum of rounded taps)^2 removes the systematic
    // scale error of fp16 conv weights (applied to all 4 maps in epilogue).
    GW gw;
    double gd[NTAP], gsum = 0.0;
    for (int i = 0; i < NTAP; ++i) {
        double x = (double)(i - 5);
        gd[i] = exp(-(x * x) / 4.5);
        gsum += gd[i];
    }
    double wsumr = 0.0;
    for (int i = 0; i < NTAP; ++i) {
        gw.g[i] = fp16_rtne(gd[i] / gsum);
        wsumr += (double)gw.g[i];
    }
    gw.cm = (float)(1.0 / (wsumr * wsumr));

    patch_max_kernel<<<dim3(32, 16), 256, 0, stream>>>(mask, smallbuf);
    ssim_kernel<<<dim3(GX, GY, 48), 256, 0, stream>>>(img1, img2, smallbuf, partial, gw);
    finalize_kernel<<<1, 256, 0, stream>>>(partial, out);
}

// Round 4
// 170.459 us; speedup vs baseline: 1.0959x; 1.0315x over previous
//
#include <hip/hip_runtime.h>
#include <cmath>
#include <cstdint>
#include <cstring>

// Problem constants (B,C,H,W) = (16,3,512,512), window 11, patch 16.
#define OUTD 502          // 512 - 11 + 1
#define TSX  64           // output tile width
#define TSY  32           // output tile height (2 groups of 16)
#define SPITCH 88         // staged row pitch (f16): 176 B, 16B-mult
#define SROWS  48         // 42 data rows + 6 zero pad (B-frag k reaches 47)
#define HTP    56         // transpose buffer pitch (f16): 48 cols + pad, 112 B
#define NTAP 11
#define GX   8            // ceil(502/64)
#define GY   16           // ceil(502/32)
#define NPARTIAL (48 * GY * GX)   // 6144

typedef float    f32x4 __attribute__((ext_vector_type(4)));
typedef _Float16 f16x4 __attribute__((ext_vector_type(4)));
typedef _Float16 f16x8 __attribute__((ext_vector_type(8)));

struct GW { float g[NTAP]; float cm; };  // g: fp16-rounded weights; cm = 1/(sum g)^2

__device__ __forceinline__ f32x4 mfma_f16(f16x8 a, f16x8 b, f32x4 c) {
    return __builtin_amdgcn_mfma_f32_16x16x32_f16(a, b, c, 0, 0, 0);
}

// Kernel 1: per-patch (16x16) max of the int mask -> small[b][32][32]
__global__ __launch_bounds__(256) void patch_max_kernel(const int* __restrict__ mask,
                                                        int* __restrict__ smallbuf) {
    const int py = blockIdx.x;   // 0..31 patch row
    const int b  = blockIdx.y;   // 0..15 image
    const int tid = threadIdx.x;
    const int lane = tid & 63, wv = tid >> 6;
    const int4* m4 = (const int4*)(mask + ((size_t)b << 18) + (size_t)py * 16 * 512);
    #pragma unroll
    for (int j = 0; j < 8; ++j) {
        int px  = wv + 4 * j;
        int row = lane >> 2, q = lane & 3;
        int4 v = m4[row * 128 + px * 4 + q];
        int mx = max(max(v.x, v.y), max(v.z, v.w));
        #pragma unroll
        for (int off = 32; off >= 1; off >>= 1) mx = max(mx, __shfl_xor(mx, off));
        if (lane == 0) smallbuf[((b << 5) + py) * 32 + px] = mx;
    }
}

// Kernel 2: MFMA separable-Gaussian SSIM over a 64x32 output tile (TSY 16->32).
// Rationale (R3 counters: VALUBusy 50%, MfmaUtil 5.4%, ~45% issue-idle with
// DS-pipe audit ~400 cyc/wave): doubling the tile vertically reuses the
// H-conv/V-conv row overlap -- per output this cuts MFMA 17%, staging 19%,
// fragment/P/S work 25%, transpose traffic 25%, and halves A-frag/barrier/
// reduction fixed costs. Only the epilogue is per-output-invariant.
// Structure per map: 3 H-MFMAs (rows 0-15,16-31,32-47) -> transpose (48 cols)
// -> 2 V-MFMAs (k=0..31 for out rows 0-15; k=16..47 via +16 col offset for
// out rows 16-31). Maps processed sequentially with on-the-fly P/S frags to
// bound VGPR (~96: 6 raw frags + 8 accumulators).
__global__ __launch_bounds__(256) void ssim_kernel(const float* __restrict__ img1,
                                                   const float* __restrict__ img2,
                                                   const int* __restrict__ smallbuf,
                                                   float* __restrict__ partial, GW gw) {
    __shared__ _Float16 sA[2][SROWS][SPITCH];   // 16896 B: staged img1/img2 (f16)
    __shared__ _Float16 sHT[4][16][HTP];        //  7168 B: per-wave transpose buffers
    __shared__ _Float16 gpad[48];               // zero-padded taps: gpad[15+i]=g[i]
    __shared__ int sdil[15];                    // 3 patch-rows x 5 patch-cols
    __shared__ float wsum[4];

    const int tid  = threadIdx.x;
    const int wv   = tid >> 6, lane = tid & 63;
    const int nidx = lane & 15, quad = lane >> 4;
    const int x0 = blockIdx.x * TSX, y0 = blockIdx.y * TSY;
    const int bc = blockIdx.z;               // b*3 + c
    const size_t base = (size_t)bc << 18;    // *512*512

    // Phase 0: stage both images, rows 0..41 from global (clamped addresses:
    // clamped data only ever reaches discarded outputs), rows 42..47 zeroed
    // (finite pad for B-frag over-reads; A is zero there anyway).
    for (int i = tid; i < SROWS * 20; i += 256) {   // 960 slots
        int r = i / 20, q = i - r * 20;
        if (r < 42) {
            int gy = y0 + r;     gy = gy > 511 ? 511 : gy;
            int gx = x0 + 4 * q; gx = gx > 508 ? 508 : gx;
            size_t off = base + ((size_t)gy << 9) + gx;
            f32x4 a = *(const f32x4*)(img1 + off);
            f32x4 b = *(const f32x4*)(img2 + off);
            *(f16x4*)&sA[0][r][4 * q] = __builtin_convertvector(a, f16x4);
            *(f16x4*)&sA[1][r][4 * q] = __builtin_convertvector(b, f16x4);
        } else {
            f16x4 z = {};
            *(f16x4*)&sA[0][r][4 * q] = z;
            *(f16x4*)&sA[1][r][4 * q] = z;
        }
    }

    // padded tap table (indices 15..25 hold g[0..10], rest zero)
    if (tid < 48) {
        int k = tid - 15;
        int kc = k < 0 ? 0 : (k > 10 ? 10 : k);      // clamp: no speculative OOB
        gpad[tid] = (k == kc) ? (_Float16)gw.g[kc] : (_Float16)0.f;
    }

    // fused 3x3 dilation lookup: tile spans patch rows 2*by .. 2*by+2 (window
    // reaches y0+41), patch cols bx*4 .. bx*4+4.
    if (tid >= 192 && tid < 207) {
        int t = tid - 192;
        int tr = t / 5, tc = t - tr * 5;
        int pr = 2 * (int)blockIdx.y + tr;
        int pc = (int)blockIdx.x * 4 + tc;
        int acc = 0;
        if (pr < 32 && pc < 32) {
            const int* sb = smallbuf + ((bc / 3) << 10);
            #pragma unroll
            for (int dy = -1; dy <= 1; ++dy)
                #pragma unroll
                for (int dx = -1; dx <= 1; ++dx) {
                    int ny = pr + dy, nx = pc + dx;
                    if (ny >= 0 && ny < 32 && nx >= 0 && nx < 32) acc |= sb[(ny << 5) + nx];
                }
        }
        sdil[t] = acc ? 1 : 0;
    }
    __syncthreads();

    // Toeplitz A-frag (shared by all passes): A[m=nidx][k=quad*8+j] = g[k-m].
    f16x8 af;
    {
        const _Float16* gp = &gpad[quad * 8 - nidx + 15];
        #pragma unroll
        for (int j = 0; j < 8; ++j) af[j] = gp[j];
    }

    // This wave handles output cols cb..cb+15 of the tile.
    const int cb = 16 * wv;

    // Raw a/b B-frags for 3 row-halves: lane = row 16h+nidx,
    // cols cb + quad*8 .. +7 (contiguous, 16B-aligned).
    f16x8 a0 = *(const f16x8*)&sA[0][nidx][cb + quad * 8];
    f16x8 b0 = *(const f16x8*)&sA[1][nidx][cb + quad * 8];
    f16x8 a1 = *(const f16x8*)&sA[0][16 + nidx][cb + quad * 8];
    f16x8 b1 = *(const f16x8*)&sA[1][16 + nidx][cb + quad * 8];
    f16x8 a2 = *(const f16x8*)&sA[0][32 + nidx][cb + quad * 8];
    f16x8 b2 = *(const f16x8*)&sA[1][32 + nidx][cb + quad * 8];

    // Per map: 3 H-MFMAs -> transpose through sHT[wv] -> 2 V-MFMAs.
    // P/S frags built on the fly (packed f16 ops) to bound register pressure.
    // All LDS deps are intra-wave (in-order DS pipe + compiler lgkmcnt waits);
    // next map's transpose writes are program-ordered after this map's reads.
    f32x4 acca[4], accb[4];
    #pragma unroll
    for (int mm = 0; mm < 4; ++mm) {
        f16x8 f0, f1, f2;
        if (mm == 0)      { f0 = a0; f1 = a1; f2 = a2; }
        else if (mm == 1) { f0 = b0; f1 = b1; f2 = b2; }
        else if (mm == 2) { f0 = a0 * b0; f1 = a1 * b1; f2 = a2 * b2; }
        else              { f0 = a0 * a0 + b0 * b0;
                            f1 = a1 * a1 + b1 * b1;
                            f2 = a2 * a2 + b2 * b2; }
        f32x4 z = {0.f, 0.f, 0.f, 0.f};
        f32x4 c0 = mfma_f16(af, f0, z);   // H-conv rows 0..15
        f32x4 c1 = mfma_f16(af, f1, z);   // rows 16..31
        f32x4 c2 = mfma_f16(af, f2, z);   // rows 32..47
        // C layout: row(m=x') = quad*4+r, col(n=data row) = nidx
        #pragma unroll
        for (int r = 0; r < 4; ++r) {
            sHT[wv][quad * 4 + r][nidx]      = (_Float16)c0[r];
            sHT[wv][quad * 4 + r][16 + nidx] = (_Float16)c1[r];
            sHT[wv][quad * 4 + r][32 + nidx] = (_Float16)c2[r];
        }
        // V-pass B-frags: B[k][n=x'=nidx]; group a: k=rows 0..31,
        // group b: k=rows 16..47 (same Toeplitz A, +16 col offset).
        f16x8 hba = *(const f16x8*)&sHT[wv][nidx][quad * 8];
        f16x8 hbb = *(const f16x8*)&sHT[wv][nidx][16 + quad * 8];
        acca[mm] = mfma_f16(af, hba, z);
        accb[mm] = mfma_f16(af, hbb, z);
    }

    // Epilogue: lane holds 4 maps x 8 pixels: group a at y = y0+quad*4+r,
    // group b at y = y0+16+quad*4+r, x = x0+cb+nidx.
    const float C1v = 1e-4f, C2v = 9e-4f;  // L = 1 (inputs uniform [0,1))
    const float cm = gw.cm;
    float lsum = 0.f;
    {
        const int xl = cb + nidx;
        const int x = x0 + xl;
        if (x < OUTD) {
            const int lc0 = xl >> 4, lc1 = (xl + 10) >> 4;
            const int p0 = sdil[lc0]      & sdil[lc1];
            const int p1 = sdil[5 + lc0]  & sdil[5 + lc1];
            const int p2 = sdil[10 + lc0] & sdil[10 + lc1];

#define SSIM_PX(ACC, r, valid)                                                \
            {                                                                 \
                float mu1 = ACC[0][r] * cm, mu2 = ACC[1][r] * cm;             \
                float Sab = ACC[2][r] * cm, Sss = ACC[3][r] * cm;             \
                float mu1s = mu1 * mu1, mu2s = mu2 * mu2, mu12 = mu1 * mu2;   \
                float sg12 = Sab - mu12;                                      \
                float sigS = Sss - mu1s - mu2s;                               \
                float num = (2.f * mu12 + C1v) * (2.f * sg12 + C2v);          \
                float den = (mu1s + mu2s + C1v) * (sigS + C2v);               \
                if (valid) lsum += __fdividef(num, den);                      \
            }

            #pragma unroll
            for (int r = 0; r < 4; ++r) {
                int q4r = quad * 4 + r;
                int cond = q4r < 6;   // window stays within patch-row stripe
                // group a: y = y0 + q4r <= 495 < OUTD always (y0 <= 480)
                {
                    int va = cond ? p0 : (p0 & p1);
                    SSIM_PX(acca, r, va)
                }
                // group b: y = y0 + 16 + q4r, may exceed OUTD
                {
                    int y = y0 + 16 + q4r;
                    int vb = cond ? p1 : (p1 & p2);
                    vb = (y < OUTD) ? vb : 0;
                    SSIM_PX(accb, r, vb)
                }
            }
#undef SSIM_PX
        }
    }

    // block reduction -> one float partial per block (deterministic, no atomics)
    #pragma unroll
    for (int off = 32; off >= 1; off >>= 1) lsum += __shfl_xor(lsum, off);
    if ((tid & 63) == 0) wsum[tid >> 6] = lsum;
    __syncthreads();
    if (tid == 0)
        partial[((int)blockIdx.z * GY + (int)blockIdx.y) * GX + (int)blockIdx.x] =
            wsum[0] + wsum[1] + wsum[2] + wsum[3];
}

// Kernel 3: reduce partials, divide by element count
__global__ __launch_bounds__(256) void finalize_kernel(const float* __restrict__ partial,
                                                       float* __restrict__ out) {
    __shared__ double sd[256];
    double s = 0.0;
    const f32x4* p4 = (const f32x4*)partial;
    for (int i = threadIdx.x; i < NPARTIAL / 4; i += 256) {
        f32x4 vv = p4[i];
        s += (double)vv.x + (double)vv.y + (double)vv.z + (double)vv.w;
    }
    sd[threadIdx.x] = s;
    __syncthreads();
    for (int st = 128; st >= 1; st >>= 1) {
        if (threadIdx.x < st) sd[threadIdx.x] += sd[threadIdx.x + st];
        __syncthreads();
    }
    if (threadIdx.x == 0) out[0] = (float)(sd[0] / 12096192.0);  // 16*3*502*502
}

// Round a positive normal double to the nearest fp16-representable float (RTNE).
static inline float fp16_rtne(double x) {
    float f = (float)x;
    uint32_t u; memcpy(&u, &f, 4);
    // drop 13 mantissa bits (23 -> 10), RTNE with carry into exponent
    u = (u + 0xFFFu + ((u >> 13) & 1u)) & ~0x1FFFu;
    memcpy(&f, &u, 4);
    return f;
}

extern "C" void kernel_launch(void* const* d_in, const int* in_sizes, int n_in,
                              void* d_out, int out_size, void* d_ws, size_t ws_size,
                              hipStream_t stream) {
    const float* img1 = (const float*)d_in[0];
    const float* img2 = (const float*)d_in[1];
    const int*   mask = (const int*)d_in[2];
    float* out = (float*)d_out;

    char* ws = (char*)d_ws;
    float* partial  = (float*)ws;                        // 6144 floats
    int*   smallbuf = (int*)(ws + NPARTIAL * 4);         // 16*32*32 ints

    // Gaussian(sigma=1.5), normalized in double, then each tap rounded to
    // fp16 (RTNE). cm = 1/(sum of rounded taps)^2 removes the systematic
    // scale error of fp16 conv weights (applied to all 4 maps in epilogue).
    GW gw;
    double gd[NTAP], gsum = 0.0;
    for (int i = 0; i < NTAP; ++i) {
        double x = (double)(i - 5);
        gd[i] = exp(-(x * x) / 4.5);
        gsum += gd[i];
    }
    double wsumr = 0.0;
    for (int i = 0; i < NTAP; ++i) {
        gw.g[i] = fp16_rtne(gd[i] / gsum);
        wsumr += (double)gw.g[i];
    }
    gw.cm = (float)(1.0 / (wsumr * wsumr));

    patch_max_kernel<<<dim3(32, 16), 256, 0, stream>>>(mask, smallbuf);
    ssim_kernel<<<dim3(GX, GY, 48), 256, 0, stream>>>(img1, img2, smallbuf, partial, gw);
    finalize_kernel<<<1, 256, 0, stream>>>(partial, out);
}

// Round 5
// 166.767 us; speedup vs baseline: 1.1202x; 1.0221x over previous
//
#include <hip/hip_runtime.h>
#include <cmath>
#include <cstdint>
#include <cstring>

// Problem constants (B,C,H,W) = (16,3,512,512), window 11, patch 16.
#define OUTD 502          // 512 - 11 + 1
#define TSX  64           // output tile width
#define TSY  32           // output tile height (2 groups of 16)
#define SPITCH 88         // staged row pitch (f16): 176 B, 16B-mult
#define SROWS  48         // 42 data rows + 6 zero pad (B-frag k reaches 47)
#define HT2P   20         // transpose buffer row pitch (f16): 40 B
#define NTAP 11
#define GX   8            // ceil(502/64)
#define GY   16           // ceil(502/32)
#define NPARTIAL (48 * GY * GX)   // 6144

typedef float    f32x2 __attribute__((ext_vector_type(2)));
typedef float    f32x4 __attribute__((ext_vector_type(4)));
typedef _Float16 f16x4 __attribute__((ext_vector_type(4)));
typedef _Float16 f16x8 __attribute__((ext_vector_type(8)));
typedef __attribute__((address_space(3))) const _Float16 lds_cf16;

struct GW { float g[NTAP]; float cm; };  // g: fp16-rounded weights; cm = 1/(sum g)^2

__device__ __forceinline__ f32x4 mfma_f16(f16x8 a, f16x8 b, f32x4 c) {
    return __builtin_amdgcn_mfma_f32_16x16x32_f16(a, b, c, 0, 0, 0);
}

// Kernel 1: per-patch (16x16) max of the int mask -> small[b][32][32]
__global__ __launch_bounds__(256) void patch_max_kernel(const int* __restrict__ mask,
                                                        int* __restrict__ smallbuf) {
    const int py = blockIdx.x;   // 0..31 patch row
    const int b  = blockIdx.y;   // 0..15 image
    const int tid = threadIdx.x;
    const int lane = tid & 63, wv = tid >> 6;
    const int4* m4 = (const int4*)(mask + ((size_t)b << 18) + (size_t)py * 16 * 512);
    #pragma unroll
    for (int j = 0; j < 8; ++j) {
        int px  = wv + 4 * j;
        int row = lane >> 2, q = lane & 3;
        int4 v = m4[row * 128 + px * 4 + q];
        int mx = max(max(v.x, v.y), max(v.z, v.w));
        #pragma unroll
        for (int off = 32; off >= 1; off >>= 1) mx = max(mx, __shfl_xor(mx, off));
        if (lane == 0) smallbuf[((b << 5) + py) * 32 + px] = mx;
    }
}

// Kernel 2: MFMA separable-Gaussian SSIM over a 64x32 output tile.
// R5 revision (R4 counters: all pipes <50% busy -> issue/latency-bound; the
// per-map serial chain H-MFMA -> 12x ds_write_b16 -> 2x ds_read_b128 -> V-MFMA
// is the exposed-latency path, and the b16 writes were the bank-conflict source):
//  (a) H->V hand-off via hardware transpose read (T10): store H results
//      UN-transposed row-major sHT[y][x'] (rows padded to 40 B). MFMA C gives
//      each lane 4 consecutive-x' values -> 3x ds_write_b64 per map
//      (conflict-free, bank = 10*n' mod 32). V-pass B-frag = 4x
//      ds_read_b64_tr_b16 from one per-lane addr + offsets {0,160,640,800}
//      (lane(q,m) fetches word (y = Ybase+8q+4h+(m>>2), w=m&3); HW
//      redistributes within 16-lane groups per m162's measured mapping).
//      DS ops/map: 14 -> 7. Rule #18: lgkmcnt(0) + sched_barrier(0) before
//      the V-MFMAs; "memory" clobber orders asm vs compiler ds_writes.
//  (b) Epilogue on f32x2 (pairs group-a/group-b pixels) -> v_pk_*_f32 halves
//      the ~100 epilogue VALU ops; divides stay scalar; IEEE-identical.
__global__ __launch_bounds__(256) void ssim_kernel(const float* __restrict__ img1,
                                                   const float* __restrict__ img2,
                                                   const int* __restrict__ smallbuf,
                                                   float* __restrict__ partial, GW gw) {
    __shared__ __align__(16) _Float16 sA[2][SROWS][SPITCH];  // 16896 B staged imgs
    __shared__ __align__(16) _Float16 sHT[4][SROWS][HT2P];   //  7680 B per-wave H-results
    __shared__ _Float16 gpad[48];               // zero-padded taps: gpad[15+i]=g[i]
    __shared__ int sdil[15];                    // 3 patch-rows x 5 patch-cols
    __shared__ float wsum[4];

    const int tid  = threadIdx.x;
    const int wv   = tid >> 6, lane = tid & 63;
    const int nidx = lane & 15, quad = lane >> 4;
    const int x0 = blockIdx.x * TSX, y0 = blockIdx.y * TSY;
    const int bc = blockIdx.z;               // b*3 + c
    const size_t base = (size_t)bc << 18;    // *512*512

    // Phase 0: stage both images, rows 0..41 from global (clamped addresses:
    // clamped data only ever reaches discarded outputs), rows 42..47 zeroed
    // (finite pad for B-frag over-reads; A is zero there anyway).
    for (int i = tid; i < SROWS * 20; i += 256) {   // 960 slots
        int r = i / 20, q = i - r * 20;
        if (r < 42) {
            int gy = y0 + r;     gy = gy > 511 ? 511 : gy;
            int gx = x0 + 4 * q; gx = gx > 508 ? 508 : gx;
            size_t off = base + ((size_t)gy << 9) + gx;
            f32x4 a = *(const f32x4*)(img1 + off);
            f32x4 b = *(const f32x4*)(img2 + off);
            *(f16x4*)&sA[0][r][4 * q] = __builtin_convertvector(a, f16x4);
            *(f16x4*)&sA[1][r][4 * q] = __builtin_convertvector(b, f16x4);
        } else {
            f16x4 z = {};
            *(f16x4*)&sA[0][r][4 * q] = z;
            *(f16x4*)&sA[1][r][4 * q] = z;
        }
    }

    // padded tap table (indices 15..25 hold g[0..10], rest zero)
    if (tid < 48) {
        int k = tid - 15;
        int kc = k < 0 ? 0 : (k > 10 ? 10 : k);      // clamp: no speculative OOB
        gpad[tid] = (k == kc) ? (_Float16)gw.g[kc] : (_Float16)0.f;
    }

    // fused 3x3 dilation lookup: tile spans patch rows 2*by .. 2*by+2 (window
    // reaches y0+41), patch cols bx*4 .. bx*4+4.
    if (tid >= 192 && tid < 207) {
        int t = tid - 192;
        int tr = t / 5, tc = t - tr * 5;
        int pr = 2 * (int)blockIdx.y + tr;
        int pc = (int)blockIdx.x * 4 + tc;
        int acc = 0;
        if (pr < 32 && pc < 32) {
            const int* sb = smallbuf + ((bc / 3) << 10);
            #pragma unroll
            for (int dy = -1; dy <= 1; ++dy)
                #pragma unroll
                for (int dx = -1; dx <= 1; ++dx) {
                    int ny = pr + dy, nx = pc + dx;
                    if (ny >= 0 && ny < 32 && nx >= 0 && nx < 32) acc |= sb[(ny << 5) + nx];
                }
        }
        sdil[t] = acc ? 1 : 0;
    }
    __syncthreads();

    // Toeplitz A-frag (shared by all passes): A[m=nidx][k=quad*8+j] = g[k-m].
    f16x8 af;
    {
        const _Float16* gp = &gpad[quad * 8 - nidx + 15];
        #pragma unroll
        for (int j = 0; j < 8; ++j) af[j] = gp[j];
    }

    // This wave handles output cols cb..cb+15 of the tile.
    const int cb = 16 * wv;

    // Raw a/b B-frags for 3 row-halves: lane = row 16h+nidx,
    // cols cb + quad*8 .. +7 (contiguous, 16B-aligned).
    f16x8 a0 = *(const f16x8*)&sA[0][nidx][cb + quad * 8];
    f16x8 b0 = *(const f16x8*)&sA[1][nidx][cb + quad * 8];
    f16x8 a1 = *(const f16x8*)&sA[0][16 + nidx][cb + quad * 8];
    f16x8 b1 = *(const f16x8*)&sA[1][16 + nidx][cb + quad * 8];
    f16x8 a2 = *(const f16x8*)&sA[0][32 + nidx][cb + quad * 8];
    f16x8 b2 = *(const f16x8*)&sA[1][32 + nidx][cb + quad * 8];

    // Transpose-buffer addresses (per-wave region sHT[wv], 40 B rows):
    // write: lane(quad,nidx) holds (x' = 4*quad+r, y = 16g+nidx) -> word at
    //        row 16g+nidx, col 4*quad  (one b64 per g; +320 f16 per g).
    _Float16* wp = &sHT[wv][nidx][quad * 4];
    // tr read: lane(q,m) fetches word (y = 8q + (m>>2) [+4h +16G], w = m&3).
    lds_cf16* rp = (lds_cf16*)&sHT[wv][8 * quad + (nidx >> 2)][4 * (nidx & 3)];

    // Per map: 3 H-MFMAs -> row-major sHT -> tr-read -> 2 V-MFMAs.
    f32x4 acca[4], accb[4];
    #pragma unroll
    for (int mm = 0; mm < 4; ++mm) {
        f16x8 f0, f1, f2;
        if (mm == 0)      { f0 = a0; f1 = a1; f2 = a2; }
        else if (mm == 1) { f0 = b0; f1 = b1; f2 = b2; }
        else if (mm == 2) { f0 = a0 * b0; f1 = a1 * b1; f2 = a2 * b2; }
        else              { f0 = a0 * a0 + b0 * b0;
                            f1 = a1 * a1 + b1 * b1;
                            f2 = a2 * a2 + b2 * b2; }
        f32x4 z = {0.f, 0.f, 0.f, 0.f};
        f32x4 c0 = mfma_f16(af, f0, z);   // H-conv rows 0..15
        f32x4 c1 = mfma_f16(af, f1, z);   // rows 16..31
        f32x4 c2 = mfma_f16(af, f2, z);   // rows 32..47
        // C layout: x' = quad*4+r (consecutive r!), y = data row = nidx + 16g
        *(f16x4*)(wp)       = __builtin_convertvector(c0, f16x4);
        *(f16x4*)(wp + 320) = __builtin_convertvector(c1, f16x4);
        *(f16x4*)(wp + 640) = __builtin_convertvector(c2, f16x4);
        // V-pass B-frags via HW transpose read. offsets (bytes):
        //   group a (y=0..31):  h0 -> 0,   h1 -> +4 rows = 160
        //   group b (y=16..47): h0 -> 640, h1 -> 800
        f16x4 r0, r1, r2, r3;
        asm volatile("ds_read_b64_tr_b16 %0, %4 offset:0\n\t"
                     "ds_read_b64_tr_b16 %1, %4 offset:160\n\t"
                     "ds_read_b64_tr_b16 %2, %4 offset:640\n\t"
                     "ds_read_b64_tr_b16 %3, %4 offset:800"
                     : "=&v"(r0), "=&v"(r1), "=&v"(r2), "=&v"(r3)
                     : "v"(rp) : "memory");
        asm volatile("s_waitcnt lgkmcnt(0)" ::: "memory");
        __builtin_amdgcn_sched_barrier(0);   // rule #18: keep MFMA after the wait
        f16x8 hba = __builtin_shufflevector(r0, r1, 0, 1, 2, 3, 4, 5, 6, 7);
        f16x8 hbb = __builtin_shufflevector(r2, r3, 0, 1, 2, 3, 4, 5, 6, 7);
        acca[mm] = mfma_f16(af, hba, z);
        accb[mm] = mfma_f16(af, hbb, z);
    }

    // Epilogue: lane holds 4 maps x 8 pixels: group a at y = y0+quad*4+r,
    // group b at y = y0+16+quad*4+r, x = x0+cb+nidx. f32x2 packs (a,b).
    const float C1v = 1e-4f, C2v = 9e-4f;  // L = 1 (inputs uniform [0,1))
    const float cm = gw.cm;
    float lsum = 0.f;
    {
        const int xl = cb + nidx;
        const int x = x0 + xl;
        if (x < OUTD) {
            const int lc0 = xl >> 4, lc1 = (xl + 10) >> 4;
            const int p0 = sdil[lc0]      & sdil[lc1];
            const int p1 = sdil[5 + lc0]  & sdil[5 + lc1];
            const int p2 = sdil[10 + lc0] & sdil[10 + lc1];

            #pragma unroll
            for (int r = 0; r < 4; ++r) {
                int q4r = quad * 4 + r;
                int cond = q4r < 6;   // window stays within patch-row stripe
                int va = cond ? p0 : (p0 & p1);              // group a always in-range
                int yb = y0 + 16 + q4r;
                int vb = cond ? p1 : (p1 & p2);
                vb = (yb < OUTD) ? vb : 0;
                f32x2 mu1 = {acca[0][r], accb[0][r]};
                f32x2 mu2 = {acca[1][r], accb[1][r]};
                f32x2 Sab = {acca[2][r], accb[2][r]};
                f32x2 Sss = {acca[3][r], accb[3][r]};
                mu1 *= cm; mu2 *= cm; Sab *= cm; Sss *= cm;
                f32x2 mu1s = mu1 * mu1, mu2s = mu2 * mu2, mu12 = mu1 * mu2;
                f32x2 sg12 = Sab - mu12;
                f32x2 sigS = Sss - mu1s - mu2s;
                f32x2 num = (2.f * mu12 + C1v) * (2.f * sg12 + C2v);
                f32x2 den = (mu1s + mu2s + C1v) * (sigS + C2v);
                if (va) lsum += __fdividef(num[0], den[0]);
                if (vb) lsum += __fdividef(num[1], den[1]);
            }
        }
    }

    // block reduction -> one float partial per block (deterministic, no atomics)
    #pragma unroll
    for (int off = 32; off >= 1; off >>= 1) lsum += __shfl_xor(lsum, off);
    if ((tid & 63) == 0) wsum[tid >> 6] = lsum;
    __syncthreads();
    if (tid == 0)
        partial[((int)blockIdx.z * GY + (int)blockIdx.y) * GX + (int)blockIdx.x] =
            wsum[0] + wsum[1] + wsum[2] + wsum[3];
}

// Kernel 3: reduce partials, divide by element count
__global__ __launch_bounds__(256) void finalize_kernel(const float* __restrict__ partial,
                                                       float* __restrict__ out) {
    __shared__ double sd[256];
    double s = 0.0;
    const f32x4* p4 = (const f32x4*)partial;
    for (int i = threadIdx.x; i < NPARTIAL / 4; i += 256) {
        f32x4 vv = p4[i];
        s += (double)vv.x + (double)vv.y + (double)vv.z + (double)vv.w;
    }
    sd[threadIdx.x] = s;
    __syncthreads();
    for (int st = 128; st >= 1; st >>= 1) {
        if (threadIdx.x < st) sd[threadIdx.x] += sd[threadIdx.x + st];
        __syncthreads();
    }
    if (threadIdx.x == 0) out[0] = (float)(sd[0] / 12096192.0);  // 16*3*502*502
}

// Round a positive normal double to the nearest fp16-representable float (RTNE).
static inline float fp16_rtne(double x) {
    float f = (float)x;
    uint32_t u; memcpy(&u, &f, 4);
    // drop 13 mantissa bits (23 -> 10), RTNE with carry into exponent
    u = (u + 0xFFFu + ((u >> 13) & 1u)) & ~0x1FFFu;
    memcpy(&f, &u, 4);
    return f;
}

extern "C" void kernel_launch(void* const* d_in, const int* in_sizes, int n_in,
                              void* d_out, int out_size, void* d_ws, size_t ws_size,
                              hipStream_t stream) {
    const float* img1 = (const float*)d_in[0];
    const float* img2 = (const float*)d_in[1];
    const int*   mask = (const int*)d_in[2];
    float* out = (float*)d_out;

    char* ws = (char*)d_ws;
    float* partial  = (float*)ws;                        // 6144 floats
    int*   smallbuf = (int*)(ws + NPARTIAL * 4);         // 16*32*32 ints

    // Gaussian(sigma=1.5), normalized in double, then each tap rounded to
    // fp16 (RTNE). cm = 1/(sum of rounded taps)^2 removes the systematic
    // scale error of fp16 conv weights (applied to all 4 maps in epilogue).
    GW gw;
    double gd[NTAP], gsum = 0.0;
    for (int i = 0; i < NTAP; ++i) {
        double x = (double)(i - 5);
        gd[i] = exp(-(x * x) / 4.5);
        gsum += gd[i];
    }
    double wsumr = 0.0;
    for (int i = 0; i < NTAP; ++i) {
        gw.g[i] = fp16_rtne(gd[i] / gsum);
        wsumr += (double)gw.g[i];
    }
    gw.cm = (float)(1.0 / (wsumr * wsumr));

    patch_max_kernel<<<dim3(32, 16), 256, 0, stream>>>(mask, smallbuf);
    ssim_kernel<<<dim3(GX, GY, 48), 256, 0, stream>>>(img1, img2, smallbuf, partial, gw);
    finalize_kernel<<<1, 256, 0, stream>>>(partial, out);
}

// Round 6
// 166.261 us; speedup vs baseline: 1.1236x; 1.0030x over previous
//
#include <hip/hip_runtime.h>
#include <cmath>
#include <cstdint>
#include <cstring>

// Problem constants (B,C,H,W) = (16,3,512,512), window 11, patch 16.
#define OUTD 502          // 512 - 11 + 1
#define TSX  64           // output tile width
#define TSY  32           // output tile height (2 groups of 16)
#define HT2P   20         // transpose buffer row pitch (f16): 40 B
#define NTAP 11
#define GX   8            // ceil(502/64)
#define GY   16           // ceil(502/32)
#define NPARTIAL (48 * GY * GX)   // 6144

typedef float    f32x2 __attribute__((ext_vector_type(2)));
typedef float    f32x4 __attribute__((ext_vector_type(4)));
typedef _Float16 f16x4 __attribute__((ext_vector_type(4)));
typedef _Float16 f16x8 __attribute__((ext_vector_type(8)));
typedef __attribute__((address_space(3))) const _Float16 lds_cf16;

struct GW { float g[NTAP]; float cm; };  // g: fp16-rounded weights; cm = 1/(sum g)^2

__device__ __forceinline__ f32x4 mfma_f16(f16x8 a, f16x8 b, f32x4 c) {
    return __builtin_amdgcn_mfma_f32_16x16x32_f16(a, b, c, 0, 0, 0);
}

// Kernel 1: per-patch (16x16) max of the int mask -> small[b][32][32]
__global__ __launch_bounds__(256) void patch_max_kernel(const int* __restrict__ mask,
                                                        int* __restrict__ smallbuf) {
    const int py = blockIdx.x;   // 0..31 patch row
    const int b  = blockIdx.y;   // 0..15 image
    const int tid = threadIdx.x;
    const int lane = tid & 63, wv = tid >> 6;
    const int4* m4 = (const int4*)(mask + ((size_t)b << 18) + (size_t)py * 16 * 512);
    #pragma unroll
    for (int j = 0; j < 8; ++j) {
        int px  = wv + 4 * j;
        int row = lane >> 2, q = lane & 3;
        int4 v = m4[row * 128 + px * 4 + q];
        int mx = max(max(v.x, v.y), max(v.z, v.w));
        #pragma unroll
        for (int off = 32; off >= 1; off >>= 1) mx = max(mx, __shfl_xor(mx, off));
        if (lane == 0) smallbuf[((b << 5) + py) * 32 + px] = mx;
    }
}

// Kernel 2: MFMA separable-Gaussian SSIM over a 64x32 output tile.
// R6 revision. R5 counters showed SQ_LDS_BANK_CONFLICT identical to R4
// (1,812,480) despite replacing the whole transpose path -> all conflicts
// and most DS traffic were in the sA staging loop + sA b128 fragment reads.
// All pipes <50% busy -> latency-bound; the staging pipeline (960-slot
// global->LDS loop + vmcnt(0) barrier drain + re-read) was the largest
// serial structure. So: sA is REMOVED -- each lane loads its B-frag rows
// directly from global (2x dwordx4, 32B-aligned, L2/L3-resident) and
// converts to f16x8 in-register. Clamp semantics preserve correctness:
// clamped/out-of-range data only reaches zero-weighted taps (g[k-m]=0 for
// rows 42..47 at valid outputs) or masked-off outputs, and is finite.
// LDS drops 25.1 -> 8.0 KB. Transpose hand-off (hw tr-read), packed f32x2
// epilogue, and reduction are unchanged from R5.
__global__ __launch_bounds__(256) void ssim_kernel(const float* __restrict__ img1,
                                                   const float* __restrict__ img2,
                                                   const int* __restrict__ smallbuf,
                                                   float* __restrict__ partial, GW gw) {
    __shared__ __align__(16) _Float16 sHT[4][48][HT2P];   // 7680 B per-wave H-results
    __shared__ _Float16 gpad[48];               // zero-padded taps: gpad[15+i]=g[i]
    __shared__ int sdil[15];                    // 3 patch-rows x 5 patch-cols
    __shared__ float wsum[4];

    const int tid  = threadIdx.x;
    const int wv   = tid >> 6, lane = tid & 63;
    const int nidx = lane & 15, quad = lane >> 4;
    const int x0 = blockIdx.x * TSX, y0 = blockIdx.y * TSY;
    const int bc = blockIdx.z;               // b*3 + c
    const size_t base = (size_t)bc << 18;    // *512*512

    // This wave handles output cols cb..cb+15 of the tile.
    const int cb = 16 * wv;

    // Direct global->reg B-frags: lane (quad,nidx) covers row y0+16h+nidx,
    // cols gxc..gxc+7. Clamps: col base <=504 (8 f32 stay in-row), row <=511.
    // Clamped data only feeds zero-weighted taps or discarded outputs.
    int gxc = x0 + cb + quad * 8; gxc = gxc > 504 ? 504 : gxc;
    f16x8 fa[3], fb[3];
    #pragma unroll
    for (int h = 0; h < 3; ++h) {
        int gy = y0 + 16 * h + nidx; gy = gy > 511 ? 511 : gy;
        const float* p1 = img1 + base + ((size_t)gy << 9) + gxc;
        const float* p2 = img2 + base + ((size_t)gy << 9) + gxc;
        f32x4 alo = *(const f32x4*)p1, ahi = *(const f32x4*)(p1 + 4);
        f32x4 blo = *(const f32x4*)p2, bhi = *(const f32x4*)(p2 + 4);
        f16x4 al = __builtin_convertvector(alo, f16x4);
        f16x4 ah = __builtin_convertvector(ahi, f16x4);
        f16x4 bl = __builtin_convertvector(blo, f16x4);
        f16x4 bh = __builtin_convertvector(bhi, f16x4);
        fa[h] = __builtin_shufflevector(al, ah, 0, 1, 2, 3, 4, 5, 6, 7);
        fb[h] = __builtin_shufflevector(bl, bh, 0, 1, 2, 3, 4, 5, 6, 7);
    }

    // padded tap table (indices 15..25 hold g[0..10], rest zero)
    if (tid < 48) {
        int k = tid - 15;
        int kc = k < 0 ? 0 : (k > 10 ? 10 : k);      // clamp: no speculative OOB
        gpad[tid] = (k == kc) ? (_Float16)gw.g[kc] : (_Float16)0.f;
    }

    // fused 3x3 dilation lookup: tile spans patch rows 2*by .. 2*by+2 (window
    // reaches y0+41), patch cols bx*4 .. bx*4+4.
    if (tid >= 192 && tid < 207) {
        int t = tid - 192;
        int tr = t / 5, tc = t - tr * 5;
        int pr = 2 * (int)blockIdx.y + tr;
        int pc = (int)blockIdx.x * 4 + tc;
        int acc = 0;
        if (pr < 32 && pc < 32) {
            const int* sb = smallbuf + ((bc / 3) << 10);
            #pragma unroll
            for (int dy = -1; dy <= 1; ++dy)
                #pragma unroll
                for (int dx = -1; dx <= 1; ++dx) {
                    int ny = pr + dy, nx = pc + dx;
                    if (ny >= 0 && ny < 32 && nx >= 0 && nx < 32) acc |= sb[(ny << 5) + nx];
                }
        }
        sdil[t] = acc ? 1 : 0;
    }
    __syncthreads();

    // Toeplitz A-frag (shared by all passes): A[m=nidx][k=quad*8+j] = g[k-m].
    f16x8 af;
    {
        const _Float16* gp = &gpad[quad * 8 - nidx + 15];
        #pragma unroll
        for (int j = 0; j < 8; ++j) af[j] = gp[j];
    }

    // Transpose-buffer addresses (per-wave region sHT[wv], 40 B rows):
    // write: lane(quad,nidx) holds (x' = 4*quad+r, y = 16g+nidx) -> word at
    //        row 16g+nidx, col 4*quad  (one b64 per g; +320 f16 per g).
    _Float16* wp = &sHT[wv][nidx][quad * 4];
    // tr read: lane(q,m) fetches word (y = 8q + (m>>2) [+4h +16G], w = m&3).
    lds_cf16* rp = (lds_cf16*)&sHT[wv][8 * quad + (nidx >> 2)][4 * (nidx & 3)];

    // Per map: 3 H-MFMAs -> row-major sHT -> tr-read -> 2 V-MFMAs.
    f32x4 acca[4], accb[4];
    #pragma unroll
    for (int mm = 0; mm < 4; ++mm) {
        f16x8 f0, f1, f2;
        if (mm == 0)      { f0 = fa[0]; f1 = fa[1]; f2 = fa[2]; }
        else if (mm == 1) { f0 = fb[0]; f1 = fb[1]; f2 = fb[2]; }
        else if (mm == 2) { f0 = fa[0] * fb[0]; f1 = fa[1] * fb[1]; f2 = fa[2] * fb[2]; }
        else              { f0 = fa[0] * fa[0] + fb[0] * fb[0];
                            f1 = fa[1] * fa[1] + fb[1] * fb[1];
                            f2 = fa[2] * fa[2] + fb[2] * fb[2]; }
        f32x4 z = {0.f, 0.f, 0.f, 0.f};
        f32x4 c0 = mfma_f16(af, f0, z);   // H-conv rows 0..15
        f32x4 c1 = mfma_f16(af, f1, z);   // rows 16..31
        f32x4 c2 = mfma_f16(af, f2, z);   // rows 32..47
        // C layout: x' = quad*4+r (consecutive r!), y = data row = nidx + 16g
        *(f16x4*)(wp)       = __builtin_convertvector(c0, f16x4);
        *(f16x4*)(wp + 320) = __builtin_convertvector(c1, f16x4);
        *(f16x4*)(wp + 640) = __builtin_convertvector(c2, f16x4);
        // V-pass B-frags via HW transpose read. offsets (bytes):
        //   group a (y=0..31):  h0 -> 0,   h1 -> +4 rows = 160
        //   group b (y=16..47): h0 -> 640, h1 -> 800
        f16x4 r0, r1, r2, r3;
        asm volatile("ds_read_b64_tr_b16 %0, %4 offset:0\n\t"
                     "ds_read_b64_tr_b16 %1, %4 offset:160\n\t"
                     "ds_read_b64_tr_b16 %2, %4 offset:640\n\t"
                     "ds_read_b64_tr_b16 %3, %4 offset:800"
                     : "=&v"(r0), "=&v"(r1), "=&v"(r2), "=&v"(r3)
                     : "v"(rp) : "memory");
        asm volatile("s_waitcnt lgkmcnt(0)" ::: "memory");
        __builtin_amdgcn_sched_barrier(0);   // rule #18: keep MFMA after the wait
        f16x8 hba = __builtin_shufflevector(r0, r1, 0, 1, 2, 3, 4, 5, 6, 7);
        f16x8 hbb = __builtin_shufflevector(r2, r3, 0, 1, 2, 3, 4, 5, 6, 7);
        acca[mm] = mfma_f16(af, hba, z);
        accb[mm] = mfma_f16(af, hbb, z);
    }

    // Epilogue: lane holds 4 maps x 8 pixels: group a at y = y0+quad*4+r,
    // group b at y = y0+16+quad*4+r, x = x0+cb+nidx. f32x2 packs (a,b).
    const float C1v = 1e-4f, C2v = 9e-4f;  // L = 1 (inputs uniform [0,1))
    const float cm = gw.cm;
    float lsum = 0.f;
    {
        const int xl = cb + nidx;
        const int x = x0 + xl;
        if (x < OUTD) {
            const int lc0 = xl >> 4, lc1 = (xl + 10) >> 4;
            const int p0 = sdil[lc0]      & sdil[lc1];
            const int p1 = sdil[5 + lc0]  & sdil[5 + lc1];
            const int p2 = sdil[10 + lc0] & sdil[10 + lc1];

            #pragma unroll
            for (int r = 0; r < 4; ++r) {
                int q4r = quad * 4 + r;
                int cond = q4r < 6;   // window stays within patch-row stripe
                int va = cond ? p0 : (p0 & p1);              // group a always in-range
                int yb = y0 + 16 + q4r;
                int vb = cond ? p1 : (p1 & p2);
                vb = (yb < OUTD) ? vb : 0;
                f32x2 mu1 = {acca[0][r], accb[0][r]};
                f32x2 mu2 = {acca[1][r], accb[1][r]};
                f32x2 Sab = {acca[2][r], accb[2][r]};
                f32x2 Sss = {acca[3][r], accb[3][r]};
                mu1 *= cm; mu2 *= cm; Sab *= cm; Sss *= cm;
                f32x2 mu1s = mu1 * mu1, mu2s = mu2 * mu2, mu12 = mu1 * mu2;
                f32x2 sg12 = Sab - mu12;
                f32x2 sigS = Sss - mu1s - mu2s;
                f32x2 num = (2.f * mu12 + C1v) * (2.f * sg12 + C2v);
                f32x2 den = (mu1s + mu2s + C1v) * (sigS + C2v);
                if (va) lsum += __fdividef(num[0], den[0]);
                if (vb) lsum += __fdividef(num[1], den[1]);
            }
        }
    }

    // block reduction -> one float partial per block (deterministic, no atomics)
    #pragma unroll
    for (int off = 32; off >= 1; off >>= 1) lsum += __shfl_xor(lsum, off);
    if ((tid & 63) == 0) wsum[tid >> 6] = lsum;
    __syncthreads();
    if (tid == 0)
        partial[((int)blockIdx.z * GY + (int)blockIdx.y) * GX + (int)blockIdx.x] =
            wsum[0] + wsum[1] + wsum[2] + wsum[3];
}

// Kernel 3: reduce partials, divide by element count
__global__ __launch_bounds__(256) void finalize_kernel(const float* __restrict__ partial,
                                                       float* __restrict__ out) {
    __shared__ double sd[256];
    double s = 0.0;
    const f32x4* p4 = (const f32x4*)partial;
    for (int i = threadIdx.x; i < NPARTIAL / 4; i += 256) {
        f32x4 vv = p4[i];
        s += (double)vv.x + (double)vv.y + (double)vv.z + (double)vv.w;
    }
    sd[threadIdx.x] = s;
    __syncthreads();
    for (int st = 128; st >= 1; st >>= 1) {
        if (threadIdx.x < st) sd[threadIdx.x] += sd[threadIdx.x + st];
        __syncthreads();
    }
    if (threadIdx.x == 0) out[0] = (float)(sd[0] / 12096192.0);  // 16*3*502*502
}

// Round a positive normal double to the nearest fp16-representable float (RTNE).
static inline float fp16_rtne(double x) {
    float f = (float)x;
    uint32_t u; memcpy(&u, &f, 4);
    // drop 13 mantissa bits (23 -> 10), RTNE with carry into exponent
    u = (u + 0xFFFu + ((u >> 13) & 1u)) & ~0x1FFFu;
    memcpy(&f, &u, 4);
    return f;
}

extern "C" void kernel_launch(void* const* d_in, const int* in_sizes, int n_in,
                              void* d_out, int out_size, void* d_ws, size_t ws_size,
                              hipStream_t stream) {
    const float* img1 = (const float*)d_in[0];
    const float* img2 = (const float*)d_in[1];
    const int*   mask = (const int*)d_in[2];
    float* out = (float*)d_out;

    char* ws = (char*)d_ws;
    float* partial  = (float*)ws;                        // 6144 floats
    int*   smallbuf = (int*)(ws + NPARTIAL * 4);         // 16*32*32 ints

    // Gaussian(sigma=1.5), normalized in double, then each tap rounded to
    // fp16 (RTNE). cm = 1/(sum of rounded taps)^2 removes the systematic
    // scale error of fp16 conv weights (applied to all 4 maps in epilogue).
    GW gw;
    double gd[NTAP], gsum = 0.0;
    for (int i = 0; i < NTAP; ++i) {
        double x = (double)(i - 5);
        gd[i] = exp(-(x * x) / 4.5);
        gsum += gd[i];
    }
    double wsumr = 0.0;
    for (int i = 0; i < NTAP; ++i) {
        gw.g[i] = fp16_rtne(gd[i] / gsum);
        wsumr += (double)gw.g[i];
    }
    gw.cm = (float)(1.0 / (wsumr * wsumr));

    patch_max_kernel<<<dim3(32, 16), 256, 0, stream>>>(mask, smallbuf);
    ssim_kernel<<<dim3(GX, GY, 48), 256, 0, stream>>>(img1, img2, smallbuf, partial, gw);
    finalize_kernel<<<1, 256, 0, stream>>>(partial, out);
}